// Round 1
// baseline (809.083 us; speedup 1.0000x reference)
//
#include <hip/hip_runtime.h>
#include <float.h>
#include <math.h>

#define Bz    32
#define Mz    65536
#define WCz   64
#define Rz    9
#define INz   512
#define IFz   138      // 2*64 + 9 + 1
#define NBLK  64       // phase-1 blocks per batch
#define RPB   1024     // rows per phase-1 block (Mz/NBLK)

// workspace layout (float elements)
// iface  : 0      .. 4416
// q      : 4416   .. 6464   (32*64)
// qq     : 6464   .. 6496
// rv     : 6496   .. 24928  (32*9*64)
// dv     : 24928  .. 25216  (32*9)
// wpos   : 25216  .. 25504  (int, 288)
// wk     : 25504  .. 25792  (int, 288)
// nw     : 25792  .. 25796  (int)
// cand_d : 25796  .. 42180  (32*64*8)
// cand_i : 42180  .. 58564  (int)

__device__ __forceinline__ bool pless(float d1, int i1, float d2, int i2) {
    return (d1 < d2) || (d1 == d2 && i1 < i2);
}

// ---------------- A1: iface = xi @ W + b -----------------------------------
__global__ __launch_bounds__(256) void k_iface(
    const float* __restrict__ xi, const float* __restrict__ W,
    const float* __restrict__ bias, float* __restrict__ iface)
{
    int o = blockIdx.x * 256 + threadIdx.x;
    if (o >= Bz * IFz) return;
    int b = o / IFz, j = o % IFz;
    const float* x = xi + b * INz;
    float a0 = 0.f, a1 = 0.f, a2 = 0.f, a3 = 0.f;
    #pragma unroll 4
    for (int i = 0; i < INz; i += 4) {
        a0 = fmaf(x[i + 0], W[(i + 0) * IFz + j], a0);
        a1 = fmaf(x[i + 1], W[(i + 1) * IFz + j], a1);
        a2 = fmaf(x[i + 2], W[(i + 2) * IFz + j], a2);
        a3 = fmaf(x[i + 3], W[(i + 3) * IFz + j], a3);
    }
    iface[o] = (a0 + a1) + (a2 + a3) + bias[j];
}

// ---------------- A2: q, qq, ww, rv, dv, winner list -----------------------
__global__ __launch_bounds__(256) void k_prep(
    const float* __restrict__ iface,
    const float* __restrict__ read_weights,
    const float* __restrict__ read_vectors,
    const int*   __restrict__ read_positions,
    float* __restrict__ ws_q, float* __restrict__ ws_qq,
    float* __restrict__ ws_rv, float* __restrict__ ws_dv,
    int* __restrict__ ws_wpos, int* __restrict__ ws_wk, int* __restrict__ ws_nw)
{
    __shared__ float ww_s[Bz * Rz];
    __shared__ int nw_s;
    int t = threadIdx.x;
    if (t == 0) nw_s = 0;

    // q = iface[:, :64]
    for (int i = t; i < Bz * WCz; i += 256) {
        int b = i >> 6, w = i & 63;
        ws_q[i] = iface[b * IFz + w];
    }
    // ww[b,r] = sigmoid(iface[b,137]) * (ig*rw + (1-ig))
    for (int i = t; i < Bz * Rz; i += 256) {
        int b = i / Rz, r = i % Rz;
        float x    = iface[b * IFz + (IFz - 1)];
        float gate = 1.0f / (1.0f + expf(-x));
        float ig   = iface[b * IFz + 2 * WCz + r];
        float rw   = read_weights[i];
        ww_s[i] = gate * (ig * rw + (1.0f - ig));
    }
    __syncthreads();

    // qq[b] = sum q^2
    if (t < Bz) {
        float s = 0.f;
        for (int w = 0; w < WCz; w++) { float v = ws_q[t * WCz + w]; s = fmaf(v, v, s); }
        ws_qq[t] = s;
    }
    // rv[b,r,w] = read_vectors + ww[b,r] * write_vector[b,w]
    for (int i = t; i < Bz * Rz * WCz; i += 256) {
        int br = i >> 6, w = i & 63;
        int b  = br / Rz;
        ws_rv[i] = fmaf(ww_s[br], iface[b * IFz + WCz + w], read_vectors[i]);
    }
    // winner list: i is winner of its position iff no j>i writes same position
    for (int i = t; i < Bz * Rz; i += 256) {
        int p = read_positions[i];
        bool win = true;
        for (int j = i + 1; j < Bz * Rz; j++)
            if (read_positions[j] == p) { win = false; break; }
        if (win) {
            int slot = atomicAdd(&nw_s, 1);
            ws_wpos[slot] = p;
            ws_wk[slot]   = i % Rz;
        }
    }
    __syncthreads();

    // dv[b,r] = ||rv - q||^2 in reference formula form
    for (int i = t; i < Bz * Rz; i += 256) {
        int b = i / Rz;
        const float* rv = ws_rv + i * WCz;
        const float* q  = ws_q + b * WCz;
        float s1 = 0.f, s2 = 0.f;
        for (int w = 0; w < WCz; w++) {
            float v = rv[w];
            s1 = fmaf(v, v, s1);
            s2 = fmaf(v, q[w], s2);
        }
        ws_dv[i] = s1 - 2.0f * s2 + ws_qq[b];
    }
    if (t == 0) ws_nw[0] = nw_s;
}

// ---------------- P1: distances + per-block top-8 --------------------------
__global__ __launch_bounds__(256) void k_dist(
    const float* __restrict__ sparse,
    const float* __restrict__ ws_q, const float* __restrict__ ws_qq,
    const int* __restrict__ ws_wpos, const int* __restrict__ ws_nw,
    float* __restrict__ cand_d, int* __restrict__ cand_i)
{
    __shared__ float d_s[RPB];
    __shared__ unsigned int bmp[RPB / 32];
    __shared__ float md[64 * 8];
    __shared__ int   mi[64 * 8];

    int t = threadIdx.x;
    int b = blockIdx.y;
    int chunk = blockIdx.x;
    int lo = chunk * RPB;

    if (t < RPB / 32) bmp[t] = 0u;
    __syncthreads();
    int nw = ws_nw[0];
    for (int i = t; i < nw; i += 256) {
        int rel = ws_wpos[i] - lo;
        if ((unsigned)rel < (unsigned)RPB) atomicOr(&bmp[rel >> 5], 1u << (rel & 31));
    }

    int e = t & 15;          // float4 slot within row
    int g = t >> 4;          // row group (16 rows per iteration)
    const float4 q4 = *(const float4*)(ws_q + b * WCz + e * 4);
    float m0 = -2.f * q4.x, m1 = -2.f * q4.y, m2 = -2.f * q4.z, m3 = -2.f * q4.w;
    float qq = ws_qq[b];
    const float* base = sparse + ((size_t)b * Mz + lo) * WCz + e * 4;
    __syncthreads();   // bitmap ready

    #pragma unroll 1
    for (int it = 0; it < RPB / 16; it += 4) {
        float4 f[4];
        int rl[4];
        #pragma unroll
        for (int u = 0; u < 4; u++) {
            rl[u] = (it + u) * 16 + g;
            f[u] = *(const float4*)(base + (size_t)rl[u] * WCz);
        }
        #pragma unroll
        for (int u = 0; u < 4; u++) {
            float p = f[u].x * (f[u].x + m0);
            p = fmaf(f[u].y, f[u].y + m1, p);
            p = fmaf(f[u].z, f[u].z + m2, p);
            p = fmaf(f[u].w, f[u].w + m3, p);
            p += __shfl_xor(p, 1);
            p += __shfl_xor(p, 2);
            p += __shfl_xor(p, 4);
            p += __shfl_xor(p, 8);
            if (e == 0) {
                float d = p + qq;
                int r = rl[u];
                if ((bmp[r >> 5] >> (r & 31)) & 1u) d = FLT_MAX;  // written -> excluded
                d_s[r] = d;
            }
        }
    }
    __syncthreads();

    // 64 threads: local top-8 over stride-64 slices
    if (t < 64) {
        float ld[8]; int li[8];
        #pragma unroll
        for (int k = 0; k < 8; k++) { ld[k] = FLT_MAX; li[k] = 0x7FFFFFFF; }
        for (int r = t; r < RPB; r += 64) {
            float v = d_s[r];
            int idx = lo + r;
            if (pless(v, idx, ld[7], li[7])) {
                #pragma unroll
                for (int k = 7; k >= 0; k--) {
                    bool ltp = (k > 0) && pless(v, idx, ld[k - 1], li[k - 1]);
                    bool lth = pless(v, idx, ld[k], li[k]);
                    if (lth) {
                        if (ltp) { ld[k] = ld[k - 1]; li[k] = li[k - 1]; }
                        else     { ld[k] = v;         li[k] = idx; }
                    }
                }
            }
        }
        #pragma unroll
        for (int k = 0; k < 8; k++) { md[t * 8 + k] = ld[k]; mi[t * 8 + k] = li[k]; }
    }
    __syncthreads();
    // tree merge 64 -> 1 sorted-8 lists
    for (int step = 32; step >= 1; step >>= 1) {
        if (t < step) {
            float od[8]; int oi[8];
            int ia = 0, ib = 0;
            #pragma unroll
            for (int k = 0; k < 8; k++) {
                float da = md[t * 8 + ia],        db = md[(t + step) * 8 + ib];
                int   ja = mi[t * 8 + ia],        jb = mi[(t + step) * 8 + ib];
                if (pless(da, ja, db, jb)) { od[k] = da; oi[k] = ja; ia++; }
                else                       { od[k] = db; oi[k] = jb; ib++; }
            }
            #pragma unroll
            for (int k = 0; k < 8; k++) { md[t * 8 + k] = od[k]; mi[t * 8 + k] = oi[k]; }
        }
        __syncthreads();
    }
    if (t < 8) {
        cand_d[((size_t)b * NBLK + chunk) * 8 + t] = md[t];
        cand_i[((size_t)b * NBLK + chunk) * 8 + t] = mi[t];
    }
}

// ---------------- P2: merge candidates, normalize, gather, write outputs ---
__global__ __launch_bounds__(256) void k_final(
    const float* __restrict__ sparse,
    const int* __restrict__ last_used,
    const float* __restrict__ ws_rv, const float* __restrict__ ws_dv,
    const int* __restrict__ ws_wpos, const int* __restrict__ ws_wk,
    const int* __restrict__ ws_nw,
    const float* __restrict__ cand_d, const int* __restrict__ cand_i,
    float* __restrict__ out)
{
    __shared__ float cd[1024]; __shared__ int ci[1024];
    __shared__ float md[64 * 8]; __shared__ int mi[64 * 8];
    __shared__ int pos_s[Rz]; __shared__ float dist_s[Rz]; __shared__ int fk_s[Rz];

    int t = threadIdx.x;
    int b = blockIdx.x;
    int nw = ws_nw[0];

    for (int i = t; i < NBLK * 8; i += 256) {
        cd[i] = cand_d[(size_t)b * NBLK * 8 + i];
        ci[i] = cand_i[(size_t)b * NBLK * 8 + i];
    }
    for (int i = t; i < nw; i += 256) {
        cd[NBLK * 8 + i] = ws_dv[b * Rz + ws_wk[i]];   // corrected written-row distance
        ci[NBLK * 8 + i] = ws_wpos[i];
    }
    for (int i = NBLK * 8 + nw + t; i < 1024; i += 256) { cd[i] = FLT_MAX; ci[i] = 0x7FFFFFFF; }
    __syncthreads();

    if (t < 64) {
        float ld[8]; int li[8];
        #pragma unroll
        for (int k = 0; k < 8; k++) { ld[k] = FLT_MAX; li[k] = 0x7FFFFFFF; }
        for (int r = t; r < 1024; r += 64) {
            float v = cd[r]; int idx = ci[r];
            if (pless(v, idx, ld[7], li[7])) {
                #pragma unroll
                for (int k = 7; k >= 0; k--) {
                    bool ltp = (k > 0) && pless(v, idx, ld[k - 1], li[k - 1]);
                    bool lth = pless(v, idx, ld[k], li[k]);
                    if (lth) {
                        if (ltp) { ld[k] = ld[k - 1]; li[k] = li[k - 1]; }
                        else     { ld[k] = v;         li[k] = idx; }
                    }
                }
            }
        }
        #pragma unroll
        for (int k = 0; k < 8; k++) { md[t * 8 + k] = ld[k]; mi[t * 8 + k] = li[k]; }
    }
    __syncthreads();
    for (int step = 32; step >= 1; step >>= 1) {
        if (t < step) {
            float od[8]; int oi[8];
            int ia = 0, ib = 0;
            #pragma unroll
            for (int k = 0; k < 8; k++) {
                float da = md[t * 8 + ia],        db = md[(t + step) * 8 + ib];
                int   ja = mi[t * 8 + ia],        jb = mi[(t + step) * 8 + ib];
                if (pless(da, ja, db, jb)) { od[k] = da; oi[k] = ja; ia++; }
                else                       { od[k] = db; oi[k] = jb; ib++; }
            }
            #pragma unroll
            for (int k = 0; k < 8; k++) { md[t * 8 + k] = od[k]; mi[t * 8 + k] = oi[k]; }
        }
        __syncthreads();
    }

    if (t == 0) {
        float norm = 0.f;
        for (int j = 0; j < 8; j++) { dist_s[j] = md[j]; pos_s[j] = mi[j]; norm = fmaxf(norm, md[j]); }
        dist_s[8] = 0.f;
        pos_s[8]  = last_used[b];
        for (int j = 0; j < Rz; j++)
            out[Bz * 8 * WCz + b * Rz + j] = dist_s[j] / norm;     // read_weights_new
    }
    __syncthreads();

    if (t < Rz) {
        int p = pos_s[t]; int fk = -1;
        for (int i = 0; i < nw; i++)
            if (ws_wpos[i] == p) { fk = ws_wk[i]; break; }
        fk_s[t] = fk;
    }
    __syncthreads();

    // gathered (B,9,64); first 8 rows also to output 0
    for (int i = t; i < Rz * WCz; i += 256) {
        int j = i >> 6, w = i & 63;
        int p = pos_s[j]; int fk = fk_s[j];
        float v = (fk >= 0) ? ws_rv[(b * Rz + fk) * WCz + w]
                            : sparse[((size_t)b * Mz + p) * WCz + w];
        out[Bz * 8 * WCz + Bz * Rz + (b * Rz + j) * WCz + w] = v;  // gathered
        if (j < 8) out[(b * 8 + j) * WCz + w] = v;                 // gathered[:, :8, :]
    }
}

extern "C" void kernel_launch(void* const* d_in, const int* in_sizes, int n_in,
                              void* d_out, int out_size, void* d_ws, size_t ws_size,
                              hipStream_t stream) {
    const float* xi             = (const float*)d_in[0];
    const float* sparse         = (const float*)d_in[1];
    const float* read_weights   = (const float*)d_in[2];
    const float* read_vectors   = (const float*)d_in[3];
    const float* W              = (const float*)d_in[4];
    const float* bias           = (const float*)d_in[5];
    const int*   read_positions = (const int*)d_in[6];
    const int*   last_used      = (const int*)d_in[7];
    float* out = (float*)d_out;
    float* ws  = (float*)d_ws;

    float* iface   = ws + 0;
    float* ws_q    = ws + 4416;
    float* ws_qq   = ws + 6464;
    float* ws_rv   = ws + 6496;
    float* ws_dv   = ws + 24928;
    int*   ws_wpos = (int*)(ws + 25216);
    int*   ws_wk   = (int*)(ws + 25504);
    int*   ws_nw   = (int*)(ws + 25792);
    float* cand_d  = ws + 25796;
    int*   cand_i  = (int*)(ws + 42180);

    k_iface<<<dim3((Bz * IFz + 255) / 256), dim3(256), 0, stream>>>(xi, W, bias, iface);
    k_prep<<<dim3(1), dim3(256), 0, stream>>>(iface, read_weights, read_vectors,
                                              read_positions, ws_q, ws_qq, ws_rv,
                                              ws_dv, ws_wpos, ws_wk, ws_nw);
    k_dist<<<dim3(NBLK, Bz), dim3(256), 0, stream>>>(sparse, ws_q, ws_qq, ws_wpos,
                                                     ws_nw, cand_d, cand_i);
    k_final<<<dim3(Bz), dim3(256), 0, stream>>>(sparse, last_used, ws_rv, ws_dv,
                                                ws_wpos, ws_wk, ws_nw, cand_d,
                                                cand_i, out);
}

// Round 2
// 783.595 us; speedup vs baseline: 1.0325x; 1.0325x over previous
//
#include <hip/hip_runtime.h>
#include <float.h>
#include <math.h>

#define Bz    32
#define Mz    65536
#define WCz   64
#define Rz    9
#define INz   512
#define IFz   138      // 2*64 + 9 + 1
#define NBLK  64       // phase-1 blocks per batch
#define RPB   1024     // rows per phase-1 block (Mz/NBLK)

// workspace layout (float elements)
// q      : 4416   .. 6464   (32*64)
// qq     : 6464   .. 6496
// rv     : 6496   .. 24928  (32*9*64)
// dv     : 24928  .. 25216  (32*9)
// wpos   : 25216  .. 25504  (int, 288)
// wk     : 25504  .. 25792  (int, 288)
// nw     : 25792  .. 25796  (int)
// cand_d : 25796  .. 42180  (32*64*8)
// cand_i : 42180  .. 58564  (int)

__device__ __forceinline__ bool pless(float d1, int i1, float d2, int i2) {
    return (d1 < d2) || (d1 == d2 && i1 < i2);
}

// ---------------- A: fused iface GEMM + prep (one block per batch) ---------
__global__ __launch_bounds__(256) void k_prep(
    const float* __restrict__ xi, const float* __restrict__ W,
    const float* __restrict__ bias,
    const float* __restrict__ read_weights,
    const float* __restrict__ read_vectors,
    const int*   __restrict__ read_positions,
    float* __restrict__ ws_q, float* __restrict__ ws_qq,
    float* __restrict__ ws_rv, float* __restrict__ ws_dv,
    int* __restrict__ ws_wpos, int* __restrict__ ws_wk, int* __restrict__ ws_nw)
{
    __shared__ float xs[INz];
    __shared__ float if_s[IFz];
    __shared__ float ww_s[Rz];
    __shared__ float rv_s[Rz * WCz];
    __shared__ float qq_s;
    __shared__ int   pos_s[Bz * Rz];
    __shared__ int   nw_s;

    int t = threadIdx.x, b = blockIdx.x;
    for (int i = t; i < INz / 4; i += 256)
        ((float4*)xs)[i] = ((const float4*)(xi + (size_t)b * INz))[i];
    for (int i = t; i < Bz * Rz; i += 256) pos_s[i] = read_positions[i];
    if (t == 0) nw_s = 0;
    __syncthreads();

    // iface[j] = xi[b] . W[:,j] + b[j], kept in LDS only
    if (t < IFz) {
        float a0 = 0.f, a1 = 0.f, a2 = 0.f, a3 = 0.f;
        #pragma unroll 4
        for (int i = 0; i < INz; i += 4) {
            a0 = fmaf(xs[i + 0], W[(i + 0) * IFz + t], a0);
            a1 = fmaf(xs[i + 1], W[(i + 1) * IFz + t], a1);
            a2 = fmaf(xs[i + 2], W[(i + 2) * IFz + t], a2);
            a3 = fmaf(xs[i + 3], W[(i + 3) * IFz + t], a3);
        }
        if_s[t] = (a0 + a1) + (a2 + a3) + bias[t];
    }
    __syncthreads();

    // q, qq (wave 0) and ww (wave 1)
    if (t < 64) {
        float v = if_s[t];
        ws_q[b * WCz + t] = v;
        float p = v * v;
        p += __shfl_xor(p, 1);  p += __shfl_xor(p, 2);  p += __shfl_xor(p, 4);
        p += __shfl_xor(p, 8);  p += __shfl_xor(p, 16); p += __shfl_xor(p, 32);
        if (t == 0) { qq_s = p; ws_qq[b] = p; }
    } else if (t < 64 + Rz) {
        int r = t - 64;
        float g  = 1.0f / (1.0f + expf(-if_s[IFz - 1]));
        float ig = if_s[2 * WCz + r];
        ww_s[r] = g * (ig * read_weights[b * Rz + r] + (1.0f - ig));
    }
    __syncthreads();

    // rv[b,r,w] = read_vectors + ww[r] * write_vector[w]
    for (int i = t; i < Rz * WCz; i += 256) {
        int r = i >> 6, w = i & 63;
        float v = fmaf(ww_s[r], if_s[WCz + w], read_vectors[(size_t)b * Rz * WCz + i]);
        rv_s[i] = v;
        ws_rv[(size_t)b * Rz * WCz + i] = v;
    }

    // winner list (block 0 only): i wins its position iff no j>i writes same pos
    if (b == 0) {
        for (int i = t; i < Bz * Rz; i += 256) {
            int p = pos_s[i];
            bool win = true;
            for (int j = i + 1; j < Bz * Rz; j++)
                if (pos_s[j] == p) { win = false; break; }
            if (win) {
                int slot = atomicAdd(&nw_s, 1);
                ws_wpos[slot] = p;
                ws_wk[slot]   = i % Rz;
            }
        }
    }
    __syncthreads();

    // dv[b,r] = ||rv||^2 - 2 rv.q + qq   (reference formula form)
    if (t < Rz) {
        float s1 = 0.f, s2 = 0.f;
        for (int w = 0; w < WCz; w++) {
            float v = rv_s[t * WCz + w];
            s1 = fmaf(v, v, s1);
            s2 = fmaf(v, if_s[w], s2);
        }
        ws_dv[b * Rz + t] = s1 - 2.0f * s2 + qq_s;
    }
    if (b == 0 && t == 0) ws_nw[0] = nw_s;
}

// ---------------- B: distances + per-block top-8 ---------------------------
__global__ __launch_bounds__(256) void k_dist(
    const float* __restrict__ sparse,
    const float* __restrict__ ws_q, const float* __restrict__ ws_qq,
    const int* __restrict__ read_positions,
    float* __restrict__ cand_d, int* __restrict__ cand_i)
{
    __shared__ float d_s[RPB];
    __shared__ unsigned int bmp[RPB / 32];
    __shared__ float md[64 * 8];
    __shared__ int   mi[64 * 8];

    int t = threadIdx.x;
    int b = blockIdx.y;
    int chunk = blockIdx.x;
    int lo = chunk * RPB;

    if (t < RPB / 32) bmp[t] = 0u;
    __syncthreads();
    for (int i = t; i < Bz * Rz; i += 256) {
        int rel = read_positions[i] - lo;
        if ((unsigned)rel < (unsigned)RPB) atomicOr(&bmp[rel >> 5], 1u << (rel & 31));
    }

    int e = t & 15;          // float4 slot within row
    int g = t >> 4;          // row group (16 rows per pass)
    const float4 q4 = *(const float4*)(ws_q + b * WCz + e * 4);
    float m0 = -2.f * q4.x, m1 = -2.f * q4.y, m2 = -2.f * q4.z, m3 = -2.f * q4.w;
    float qq = ws_qq[b];
    const float* base = sparse + ((size_t)b * Mz + lo) * WCz + e * 4;
    __syncthreads();   // bitmap ready

    // 8 float4 loads in flight per thread (128 B/lane) to cover HBM latency
    #pragma unroll 1
    for (int it = 0; it < RPB / 16; it += 8) {
        float4 f[8];
        int rl[8];
        #pragma unroll
        for (int u = 0; u < 8; u++) {
            rl[u] = (it + u) * 16 + g;
            f[u] = *(const float4*)(base + (size_t)rl[u] * WCz);
        }
        #pragma unroll
        for (int u = 0; u < 8; u++) {
            float p = f[u].x * (f[u].x + m0);
            p = fmaf(f[u].y, f[u].y + m1, p);
            p = fmaf(f[u].z, f[u].z + m2, p);
            p = fmaf(f[u].w, f[u].w + m3, p);
            p += __shfl_xor(p, 1);
            p += __shfl_xor(p, 2);
            p += __shfl_xor(p, 4);
            p += __shfl_xor(p, 8);
            if (e == 0) {
                float d = p + qq;
                int r = rl[u];
                if ((bmp[r >> 5] >> (r & 31)) & 1u) d = FLT_MAX;  // written -> excluded
                d_s[r] = d;
            }
        }
    }
    __syncthreads();

    // 64 threads: local top-8 over stride-64 slices
    if (t < 64) {
        float ld[8]; int li[8];
        #pragma unroll
        for (int k = 0; k < 8; k++) { ld[k] = FLT_MAX; li[k] = 0x7FFFFFFF; }
        for (int r = t; r < RPB; r += 64) {
            float v = d_s[r];
            int idx = lo + r;
            if (pless(v, idx, ld[7], li[7])) {
                #pragma unroll
                for (int k = 7; k >= 0; k--) {
                    bool ltp = (k > 0) && pless(v, idx, ld[k - 1], li[k - 1]);
                    bool lth = pless(v, idx, ld[k], li[k]);
                    if (lth) {
                        if (ltp) { ld[k] = ld[k - 1]; li[k] = li[k - 1]; }
                        else     { ld[k] = v;         li[k] = idx; }
                    }
                }
            }
        }
        #pragma unroll
        for (int k = 0; k < 8; k++) { md[t * 8 + k] = ld[k]; mi[t * 8 + k] = li[k]; }
    }
    __syncthreads();
    // tree merge 64 -> 1 sorted-8 lists
    for (int step = 32; step >= 1; step >>= 1) {
        if (t < step) {
            float od[8]; int oi[8];
            int ia = 0, ib = 0;
            #pragma unroll
            for (int k = 0; k < 8; k++) {
                float da = md[t * 8 + ia],        db = md[(t + step) * 8 + ib];
                int   ja = mi[t * 8 + ia],        jb = mi[(t + step) * 8 + ib];
                if (pless(da, ja, db, jb)) { od[k] = da; oi[k] = ja; ia++; }
                else                       { od[k] = db; oi[k] = jb; ib++; }
            }
            #pragma unroll
            for (int k = 0; k < 8; k++) { md[t * 8 + k] = od[k]; mi[t * 8 + k] = oi[k]; }
        }
        __syncthreads();
    }
    if (t < 8) {
        cand_d[((size_t)b * NBLK + chunk) * 8 + t] = md[t];
        cand_i[((size_t)b * NBLK + chunk) * 8 + t] = mi[t];
    }
}

// ---------------- C: merge candidates, normalize, gather, write outputs ----
__global__ __launch_bounds__(256) void k_final(
    const float* __restrict__ sparse,
    const int* __restrict__ last_used,
    const float* __restrict__ ws_rv, const float* __restrict__ ws_dv,
    const int* __restrict__ ws_wpos, const int* __restrict__ ws_wk,
    const int* __restrict__ ws_nw,
    const float* __restrict__ cand_d, const int* __restrict__ cand_i,
    float* __restrict__ out)
{
    __shared__ float cd[1024]; __shared__ int ci[1024];
    __shared__ float md[64 * 8]; __shared__ int mi[64 * 8];
    __shared__ int pos_s[Rz]; __shared__ float dist_s[Rz]; __shared__ int fk_s[Rz];

    int t = threadIdx.x;
    int b = blockIdx.x;
    int nw = ws_nw[0];

    for (int i = t; i < NBLK * 8; i += 256) {
        cd[i] = cand_d[(size_t)b * NBLK * 8 + i];
        ci[i] = cand_i[(size_t)b * NBLK * 8 + i];
    }
    for (int i = t; i < nw; i += 256) {
        cd[NBLK * 8 + i] = ws_dv[b * Rz + ws_wk[i]];   // corrected written-row distance
        ci[NBLK * 8 + i] = ws_wpos[i];
    }
    for (int i = NBLK * 8 + nw + t; i < 1024; i += 256) { cd[i] = FLT_MAX; ci[i] = 0x7FFFFFFF; }
    __syncthreads();

    if (t < 64) {
        float ld[8]; int li[8];
        #pragma unroll
        for (int k = 0; k < 8; k++) { ld[k] = FLT_MAX; li[k] = 0x7FFFFFFF; }
        for (int r = t; r < 1024; r += 64) {
            float v = cd[r]; int idx = ci[r];
            if (pless(v, idx, ld[7], li[7])) {
                #pragma unroll
                for (int k = 7; k >= 0; k--) {
                    bool ltp = (k > 0) && pless(v, idx, ld[k - 1], li[k - 1]);
                    bool lth = pless(v, idx, ld[k], li[k]);
                    if (lth) {
                        if (ltp) { ld[k] = ld[k - 1]; li[k] = li[k - 1]; }
                        else     { ld[k] = v;         li[k] = idx; }
                    }
                }
            }
        }
        #pragma unroll
        for (int k = 0; k < 8; k++) { md[t * 8 + k] = ld[k]; mi[t * 8 + k] = li[k]; }
    }
    __syncthreads();
    for (int step = 32; step >= 1; step >>= 1) {
        if (t < step) {
            float od[8]; int oi[8];
            int ia = 0, ib = 0;
            #pragma unroll
            for (int k = 0; k < 8; k++) {
                float da = md[t * 8 + ia],        db = md[(t + step) * 8 + ib];
                int   ja = mi[t * 8 + ia],        jb = mi[(t + step) * 8 + ib];
                if (pless(da, ja, db, jb)) { od[k] = da; oi[k] = ja; ia++; }
                else                       { od[k] = db; oi[k] = jb; ib++; }
            }
            #pragma unroll
            for (int k = 0; k < 8; k++) { md[t * 8 + k] = od[k]; mi[t * 8 + k] = oi[k]; }
        }
        __syncthreads();
    }

    if (t == 0) {
        float norm = 0.f;
        for (int j = 0; j < 8; j++) { dist_s[j] = md[j]; pos_s[j] = mi[j]; norm = fmaxf(norm, md[j]); }
        dist_s[8] = 0.f;
        pos_s[8]  = last_used[b];
        for (int j = 0; j < Rz; j++)
            out[Bz * 8 * WCz + b * Rz + j] = dist_s[j] / norm;     // read_weights_new
    }
    __syncthreads();

    if (t < Rz) {
        int p = pos_s[t]; int fk = -1;
        for (int i = 0; i < nw; i++)
            if (ws_wpos[i] == p) { fk = ws_wk[i]; break; }
        fk_s[t] = fk;
    }
    __syncthreads();

    // gathered (B,9,64); first 8 rows also to output 0
    for (int i = t; i < Rz * WCz; i += 256) {
        int j = i >> 6, w = i & 63;
        int p = pos_s[j]; int fk = fk_s[j];
        float v = (fk >= 0) ? ws_rv[(b * Rz + fk) * WCz + w]
                            : sparse[((size_t)b * Mz + p) * WCz + w];
        out[Bz * 8 * WCz + Bz * Rz + (b * Rz + j) * WCz + w] = v;  // gathered
        if (j < 8) out[(b * 8 + j) * WCz + w] = v;                 // gathered[:, :8, :]
    }
}

extern "C" void kernel_launch(void* const* d_in, const int* in_sizes, int n_in,
                              void* d_out, int out_size, void* d_ws, size_t ws_size,
                              hipStream_t stream) {
    const float* xi             = (const float*)d_in[0];
    const float* sparse         = (const float*)d_in[1];
    const float* read_weights   = (const float*)d_in[2];
    const float* read_vectors   = (const float*)d_in[3];
    const float* W              = (const float*)d_in[4];
    const float* bias           = (const float*)d_in[5];
    const int*   read_positions = (const int*)d_in[6];
    const int*   last_used      = (const int*)d_in[7];
    float* out = (float*)d_out;
    float* ws  = (float*)d_ws;

    float* ws_q    = ws + 4416;
    float* ws_qq   = ws + 6464;
    float* ws_rv   = ws + 6496;
    float* ws_dv   = ws + 24928;
    int*   ws_wpos = (int*)(ws + 25216);
    int*   ws_wk   = (int*)(ws + 25504);
    int*   ws_nw   = (int*)(ws + 25792);
    float* cand_d  = ws + 25796;
    int*   cand_i  = (int*)(ws + 42180);

    k_prep<<<dim3(Bz), dim3(256), 0, stream>>>(xi, W, bias, read_weights,
                                               read_vectors, read_positions,
                                               ws_q, ws_qq, ws_rv, ws_dv,
                                               ws_wpos, ws_wk, ws_nw);
    k_dist<<<dim3(NBLK, Bz), dim3(256), 0, stream>>>(sparse, ws_q, ws_qq,
                                                     read_positions, cand_d, cand_i);
    k_final<<<dim3(Bz), dim3(256), 0, stream>>>(sparse, last_used, ws_rv, ws_dv,
                                                ws_wpos, ws_wk, ws_nw, cand_d,
                                                cand_i, out);
}

// Round 3
// 753.732 us; speedup vs baseline: 1.0734x; 1.0396x over previous
//
#include <hip/hip_runtime.h>
#include <float.h>
#include <math.h>

#define Bz    32
#define Mz    65536
#define WCz   64
#define Rz    9
#define INz   512
#define IFz   138      // 2*64 + 9 + 1
#define NBLK  64       // phase-1 blocks per batch
#define RPB   1024     // rows per phase-1 block (Mz/NBLK)

typedef float f32x4 __attribute__((ext_vector_type(4)));

__device__ __forceinline__ bool pless(float d1, int i1, float d2, int i2) {
    return (d1 < d2) || (d1 == d2 && i1 < i2);
}

// ---------------- A: fused iface GEMM + prep (one block per batch) ---------
__global__ __launch_bounds__(256) void k_prep(
    const float* __restrict__ xi, const float* __restrict__ W,
    const float* __restrict__ bias,
    const float* __restrict__ read_weights,
    const float* __restrict__ read_vectors,
    const int*   __restrict__ read_positions,
    float* __restrict__ ws_q, float* __restrict__ ws_qq,
    float* __restrict__ ws_rv, float* __restrict__ ws_dv,
    int* __restrict__ ws_wpos, int* __restrict__ ws_wk, int* __restrict__ ws_nw)
{
    __shared__ float xs[INz];
    __shared__ float if_s[IFz];
    __shared__ float ww_s[Rz];
    __shared__ float rv_s[Rz * WCz];
    __shared__ float qq_s;
    __shared__ int   pos_s[Bz * Rz];
    __shared__ int   nw_s;

    int t = threadIdx.x, b = blockIdx.x;
    for (int i = t; i < INz / 4; i += 256)
        ((float4*)xs)[i] = ((const float4*)(xi + (size_t)b * INz))[i];
    for (int i = t; i < Bz * Rz; i += 256) pos_s[i] = read_positions[i];
    if (t == 0) nw_s = 0;
    __syncthreads();

    // iface[j] = xi[b] . W[:,j] + b[j], kept in LDS only
    if (t < IFz) {
        float a0 = 0.f, a1 = 0.f, a2 = 0.f, a3 = 0.f;
        #pragma unroll 4
        for (int i = 0; i < INz; i += 4) {
            a0 = fmaf(xs[i + 0], W[(i + 0) * IFz + t], a0);
            a1 = fmaf(xs[i + 1], W[(i + 1) * IFz + t], a1);
            a2 = fmaf(xs[i + 2], W[(i + 2) * IFz + t], a2);
            a3 = fmaf(xs[i + 3], W[(i + 3) * IFz + t], a3);
        }
        if_s[t] = (a0 + a1) + (a2 + a3) + bias[t];
    }
    __syncthreads();

    // q, qq (wave 0) and ww (wave 1)
    if (t < 64) {
        float v = if_s[t];
        ws_q[b * WCz + t] = v;
        float p = v * v;
        p += __shfl_xor(p, 1);  p += __shfl_xor(p, 2);  p += __shfl_xor(p, 4);
        p += __shfl_xor(p, 8);  p += __shfl_xor(p, 16); p += __shfl_xor(p, 32);
        if (t == 0) { qq_s = p; ws_qq[b] = p; }
    } else if (t < 64 + Rz) {
        int r = t - 64;
        float g  = 1.0f / (1.0f + expf(-if_s[IFz - 1]));
        float ig = if_s[2 * WCz + r];
        ww_s[r] = g * (ig * read_weights[b * Rz + r] + (1.0f - ig));
    }
    __syncthreads();

    // rv[b,r,w] = read_vectors + ww[r] * write_vector[w]
    for (int i = t; i < Rz * WCz; i += 256) {
        int r = i >> 6, w = i & 63;
        float v = fmaf(ww_s[r], if_s[WCz + w], read_vectors[(size_t)b * Rz * WCz + i]);
        rv_s[i] = v;
        ws_rv[(size_t)b * Rz * WCz + i] = v;
    }

    // winner list (block 0 only): i wins its position iff no j>i writes same pos
    if (b == 0) {
        for (int i = t; i < Bz * Rz; i += 256) {
            int p = pos_s[i];
            bool win = true;
            for (int j = i + 1; j < Bz * Rz; j++)
                if (pos_s[j] == p) { win = false; break; }
            if (win) {
                int slot = atomicAdd(&nw_s, 1);
                ws_wpos[slot] = p;
                ws_wk[slot]   = i % Rz;
            }
        }
    }
    __syncthreads();

    // dv[b,r] = ||rv||^2 - 2 rv.q + qq   (reference formula form)
    if (t < Rz) {
        float s1 = 0.f, s2 = 0.f;
        for (int w = 0; w < WCz; w++) {
            float v = rv_s[t * WCz + w];
            s1 = fmaf(v, v, s1);
            s2 = fmaf(v, if_s[w], s2);
        }
        ws_dv[b * Rz + t] = s1 - 2.0f * s2 + qq_s;
    }
    if (b == 0 && t == 0) ws_nw[0] = nw_s;
}

// ---------------- B: distances + per-block top-8 ---------------------------
__global__ __launch_bounds__(256) void k_dist(
    const float* __restrict__ sparse,
    const float* __restrict__ ws_q, const float* __restrict__ ws_qq,
    const int* __restrict__ read_positions,
    float* __restrict__ cand_d, int* __restrict__ cand_i)
{
    __shared__ float d_s[RPB];
    __shared__ unsigned int bmp[RPB / 32];
    __shared__ float md[64 * 8];
    __shared__ int   mi[64 * 8];

    int t = threadIdx.x;
    int b = blockIdx.y;
    int chunk = blockIdx.x;
    int lo = chunk * RPB;

    if (t < RPB / 32) bmp[t] = 0u;
    __syncthreads();
    for (int i = t; i < Bz * Rz; i += 256) {
        int rel = read_positions[i] - lo;
        if ((unsigned)rel < (unsigned)RPB) atomicOr(&bmp[rel >> 5], 1u << (rel & 31));
    }

    int e = t & 15;          // float4 slot within row
    int g = t >> 4;          // row group (16 rows per pass)
    const float4 q4 = *(const float4*)(ws_q + b * WCz + e * 4);
    float m0 = -2.f * q4.x, m1 = -2.f * q4.y, m2 = -2.f * q4.z, m3 = -2.f * q4.w;
    float qq = ws_qq[b];
    const f32x4* base = (const f32x4*)(sparse + ((size_t)b * Mz + lo) * WCz + e * 4);
    __syncthreads();   // bitmap ready

    // software-pipelined: two 8-deep register buffers alternate so the next
    // 8 loads are in flight while the current 8 are consumed (no vmcnt drain)
    f32x4 fa[8], fb[8];
    #pragma unroll
    for (int u = 0; u < 8; u++)
        fa[u] = __builtin_nontemporal_load(base + (size_t)(u * 16 + g) * (WCz / 4));

    #pragma unroll 1
    for (int it = 0; it < 64; it += 16) {
        #pragma unroll
        for (int u = 0; u < 8; u++)
            fb[u] = __builtin_nontemporal_load(base + (size_t)((it + 8 + u) * 16 + g) * (WCz / 4));
        #pragma unroll
        for (int u = 0; u < 8; u++) {
            float p = fa[u].x * (fa[u].x + m0);
            p = fmaf(fa[u].y, fa[u].y + m1, p);
            p = fmaf(fa[u].z, fa[u].z + m2, p);
            p = fmaf(fa[u].w, fa[u].w + m3, p);
            p += __shfl_xor(p, 1);
            p += __shfl_xor(p, 2);
            p += __shfl_xor(p, 4);
            p += __shfl_xor(p, 8);
            if (e == 0) {
                int r = (it + u) * 16 + g;
                float d = p + qq;
                if ((bmp[r >> 5] >> (r & 31)) & 1u) d = FLT_MAX;
                d_s[r] = d;
            }
        }
        if (it + 16 < 64) {
            #pragma unroll
            for (int u = 0; u < 8; u++)
                fa[u] = __builtin_nontemporal_load(base + (size_t)((it + 16 + u) * 16 + g) * (WCz / 4));
        }
        #pragma unroll
        for (int u = 0; u < 8; u++) {
            float p = fb[u].x * (fb[u].x + m0);
            p = fmaf(fb[u].y, fb[u].y + m1, p);
            p = fmaf(fb[u].z, fb[u].z + m2, p);
            p = fmaf(fb[u].w, fb[u].w + m3, p);
            p += __shfl_xor(p, 1);
            p += __shfl_xor(p, 2);
            p += __shfl_xor(p, 4);
            p += __shfl_xor(p, 8);
            if (e == 0) {
                int r = (it + 8 + u) * 16 + g;
                float d = p + qq;
                if ((bmp[r >> 5] >> (r & 31)) & 1u) d = FLT_MAX;
                d_s[r] = d;
            }
        }
    }
    __syncthreads();

    // 64 threads: local top-8 over stride-64 slices
    if (t < 64) {
        float ld[8]; int li[8];
        #pragma unroll
        for (int k = 0; k < 8; k++) { ld[k] = FLT_MAX; li[k] = 0x7FFFFFFF; }
        for (int r = t; r < RPB; r += 64) {
            float v = d_s[r];
            int idx = lo + r;
            if (pless(v, idx, ld[7], li[7])) {
                #pragma unroll
                for (int k = 7; k >= 0; k--) {
                    bool ltp = (k > 0) && pless(v, idx, ld[k - 1], li[k - 1]);
                    bool lth = pless(v, idx, ld[k], li[k]);
                    if (lth) {
                        if (ltp) { ld[k] = ld[k - 1]; li[k] = li[k - 1]; }
                        else     { ld[k] = v;         li[k] = idx; }
                    }
                }
            }
        }
        #pragma unroll
        for (int k = 0; k < 8; k++) { md[t * 8 + k] = ld[k]; mi[t * 8 + k] = li[k]; }
    }
    __syncthreads();
    // tree merge 64 -> 1 sorted-8 lists
    for (int step = 32; step >= 1; step >>= 1) {
        if (t < step) {
            float od[8]; int oi[8];
            int ia = 0, ib = 0;
            #pragma unroll
            for (int k = 0; k < 8; k++) {
                float da = md[t * 8 + ia],        db = md[(t + step) * 8 + ib];
                int   ja = mi[t * 8 + ia],        jb = mi[(t + step) * 8 + ib];
                if (pless(da, ja, db, jb)) { od[k] = da; oi[k] = ja; ia++; }
                else                       { od[k] = db; oi[k] = jb; ib++; }
            }
            #pragma unroll
            for (int k = 0; k < 8; k++) { md[t * 8 + k] = od[k]; mi[t * 8 + k] = oi[k]; }
        }
        __syncthreads();
    }
    if (t < 8) {
        cand_d[((size_t)b * NBLK + chunk) * 8 + t] = md[t];
        cand_i[((size_t)b * NBLK + chunk) * 8 + t] = mi[t];
    }
}

// ---------------- C: merge candidates, normalize, gather, write outputs ----
__global__ __launch_bounds__(256) void k_final(
    const float* __restrict__ sparse,
    const int* __restrict__ last_used,
    const float* __restrict__ ws_rv, const float* __restrict__ ws_dv,
    const int* __restrict__ ws_wpos, const int* __restrict__ ws_wk,
    const int* __restrict__ ws_nw,
    const float* __restrict__ cand_d, const int* __restrict__ cand_i,
    float* __restrict__ out)
{
    __shared__ float cd[1024]; __shared__ int ci[1024];
    __shared__ float md[64 * 8]; __shared__ int mi[64 * 8];
    __shared__ int pos_s[Rz]; __shared__ float dist_s[Rz]; __shared__ int fk_s[Rz];

    int t = threadIdx.x;
    int b = blockIdx.x;
    int nw = ws_nw[0];

    for (int i = t; i < NBLK * 8; i += 256) {
        cd[i] = cand_d[(size_t)b * NBLK * 8 + i];
        ci[i] = cand_i[(size_t)b * NBLK * 8 + i];
    }
    for (int i = t; i < nw; i += 256) {
        cd[NBLK * 8 + i] = ws_dv[b * Rz + ws_wk[i]];   // corrected written-row distance
        ci[NBLK * 8 + i] = ws_wpos[i];
    }
    for (int i = NBLK * 8 + nw + t; i < 1024; i += 256) { cd[i] = FLT_MAX; ci[i] = 0x7FFFFFFF; }
    __syncthreads();

    if (t < 64) {
        float ld[8]; int li[8];
        #pragma unroll
        for (int k = 0; k < 8; k++) { ld[k] = FLT_MAX; li[k] = 0x7FFFFFFF; }
        for (int r = t; r < 1024; r += 64) {
            float v = cd[r]; int idx = ci[r];
            if (pless(v, idx, ld[7], li[7])) {
                #pragma unroll
                for (int k = 7; k >= 0; k--) {
                    bool ltp = (k > 0) && pless(v, idx, ld[k - 1], li[k - 1]);
                    bool lth = pless(v, idx, ld[k], li[k]);
                    if (lth) {
                        if (ltp) { ld[k] = ld[k - 1]; li[k] = li[k - 1]; }
                        else     { ld[k] = v;         li[k] = idx; }
                    }
                }
            }
        }
        #pragma unroll
        for (int k = 0; k < 8; k++) { md[t * 8 + k] = ld[k]; mi[t * 8 + k] = li[k]; }
    }
    __syncthreads();
    for (int step = 32; step >= 1; step >>= 1) {
        if (t < step) {
            float od[8]; int oi[8];
            int ia = 0, ib = 0;
            #pragma unroll
            for (int k = 0; k < 8; k++) {
                float da = md[t * 8 + ia],        db = md[(t + step) * 8 + ib];
                int   ja = mi[t * 8 + ia],        jb = mi[(t + step) * 8 + ib];
                if (pless(da, ja, db, jb)) { od[k] = da; oi[k] = ja; ia++; }
                else                       { od[k] = db; oi[k] = jb; ib++; }
            }
            #pragma unroll
            for (int k = 0; k < 8; k++) { md[t * 8 + k] = od[k]; mi[t * 8 + k] = oi[k]; }
        }
        __syncthreads();
    }

    if (t == 0) {
        float norm = 0.f;
        for (int j = 0; j < 8; j++) { dist_s[j] = md[j]; pos_s[j] = mi[j]; norm = fmaxf(norm, md[j]); }
        dist_s[8] = 0.f;
        pos_s[8]  = last_used[b];
        for (int j = 0; j < Rz; j++)
            out[Bz * 8 * WCz + b * Rz + j] = dist_s[j] / norm;     // read_weights_new
    }
    __syncthreads();

    if (t < Rz) {
        int p = pos_s[t]; int fk = -1;
        for (int i = 0; i < nw; i++)
            if (ws_wpos[i] == p) { fk = ws_wk[i]; break; }
        fk_s[t] = fk;
    }
    __syncthreads();

    // gathered (B,9,64); first 8 rows also to output 0
    for (int i = t; i < Rz * WCz; i += 256) {
        int j = i >> 6, w = i & 63;
        int p = pos_s[j]; int fk = fk_s[j];
        float v = (fk >= 0) ? ws_rv[(b * Rz + fk) * WCz + w]
                            : sparse[((size_t)b * Mz + p) * WCz + w];
        out[Bz * 8 * WCz + Bz * Rz + (b * Rz + j) * WCz + w] = v;  // gathered
        if (j < 8) out[(b * 8 + j) * WCz + w] = v;                 // gathered[:, :8, :]
    }
}

extern "C" void kernel_launch(void* const* d_in, const int* in_sizes, int n_in,
                              void* d_out, int out_size, void* d_ws, size_t ws_size,
                              hipStream_t stream) {
    const float* xi             = (const float*)d_in[0];
    const float* sparse         = (const float*)d_in[1];
    const float* read_weights   = (const float*)d_in[2];
    const float* read_vectors   = (const float*)d_in[3];
    const float* W              = (const float*)d_in[4];
    const float* bias           = (const float*)d_in[5];
    const int*   read_positions = (const int*)d_in[6];
    const int*   last_used      = (const int*)d_in[7];
    float* out = (float*)d_out;
    float* ws  = (float*)d_ws;

    float* ws_q    = ws + 4416;
    float* ws_qq   = ws + 6464;
    float* ws_rv   = ws + 6496;
    float* ws_dv   = ws + 24928;
    int*   ws_wpos = (int*)(ws + 25216);
    int*   ws_wk   = (int*)(ws + 25504);
    int*   ws_nw   = (int*)(ws + 25792);
    float* cand_d  = ws + 25796;
    int*   cand_i  = (int*)(ws + 42180);

    k_prep<<<dim3(Bz), dim3(256), 0, stream>>>(xi, W, bias, read_weights,
                                               read_vectors, read_positions,
                                               ws_q, ws_qq, ws_rv, ws_dv,
                                               ws_wpos, ws_wk, ws_nw);
    k_dist<<<dim3(NBLK, Bz), dim3(256), 0, stream>>>(sparse, ws_q, ws_qq,
                                                     read_positions, cand_d, cand_i);
    k_final<<<dim3(Bz), dim3(256), 0, stream>>>(sparse, last_used, ws_rv, ws_dv,
                                                ws_wpos, ws_wk, ws_nw, cand_d,
                                                cand_i, out);
}